// Round 2
// baseline (174.887 us; speedup 1.0000x reference)
//
#include <hip/hip_runtime.h>

// B=16, T=1024, N=1024, D=256, WIN=64
// outputs (flat): R (B,T,2D) = [A@V, Q]   : 8388608 f32
//                 alignments (B,N,T) = A^T: 16777216 f32
//                 max_att (B,T)           : 16384 f32
//
// v9: single-barrier restructure. v8 was latency-bound (59.5us, 28% HBM,
// 17.6% VALU): 4 barriers each with full vmcnt(0) drains on a 4-block/CU
// grid where kernel time == one block's critical path.
//  - QK^T via d-split: wave w owns dims [64w,64w+64). lane = window row j;
//    each lane loads its K-row quarter (16 sequential float4, L2-hot window,
//    no LDS staging). Partial dots for ALL 16 queries in registers.
//  - partials -> 16KB LDS, ONE barrier, each wave reduces its own 4 queries.
//  - softmax per wave in registers; alignment strip stored straight from
//    registers (each wave stores its own 4-column float4 per row) -> no
//    second barrier.
//  - PV reads p_lds rows its own wave wrote (lgkmcnt only, no barrier).
//  - zeroing of non-window rows + PV + R unchanged from v8.

#define BB 16
#define TT 1024
#define NN 1024
#define DD 256
#define WIN 64
#define TBLK 16          // queries per block
#define NT 256           // 4 waves; wave = d-quarter in QK^T, 4 queries in PV

#define R_ELEMS   (16u*1024u*512u)        // 8388608
#define ALN_ELEMS (16u*1024u*1024u)       // 16777216

__global__ __launch_bounds__(NT, 4) void attn_v9(
    const float* __restrict__ Q, const float* __restrict__ K,
    const float* __restrict__ V, const int* __restrict__ prev_in,
    float* __restrict__ out)
{
    __shared__ float part[4][TBLK][64];     // 16384 B: [d-quarter][t][j]
    __shared__ float p_lds[TBLK][WIN + 4];  //  4352 B: probabilities [t][j]

    float* Rout   = out;
    float* aligns = out + R_ELEMS;
    float* maxatt = out + R_ELEMS + ALN_ELEMS;

    const int tid  = threadIdx.x;
    const int lane = tid & 63;
    const int w    = __builtin_amdgcn_readfirstlane(tid >> 6);  // wave 0..3 (uniform)
    const int b    = blockIdx.x >> 6;       // 64 blocks per batch
    const int t0   = (blockIdx.x & 63) * TBLK;
    const int prev = prev_in[b];

    // ============ QK^T partials: wave w covers dims [64w, 64w+64) ============
    // lane j loads K[prev+j][64w .. 64w+63] directly (16 float4, L2-hot).
    {
        const float4* Kq = (const float4*)(K + ((size_t)b * NN + prev + lane) * DD + w * 64);
        const float*  Qw = Q + ((size_t)b * TT + t0) * DD + w * 64;   // wave-uniform

        float acc[TBLK];
        #pragma unroll
        for (int t = 0; t < TBLK; ++t) acc[t] = 0.f;

        #pragma unroll
        for (int c = 0; c < 2; ++c) {            // 2 chunks of 8 float4 (32 dims)
            float4 kreg[8];
            #pragma unroll
            for (int d4 = 0; d4 < 8; ++d4) kreg[d4] = Kq[c * 8 + d4];
            #pragma unroll
            for (int t = 0; t < TBLK; ++t) {
                #pragma unroll
                for (int d4 = 0; d4 < 8; ++d4) {
                    float4 q = ((const float4*)(Qw + t * DD))[c * 8 + d4];  // uniform
                    acc[t] = fmaf(q.x, kreg[d4].x, fmaf(q.y, kreg[d4].y,
                             fmaf(q.z, kreg[d4].z, fmaf(q.w, kreg[d4].w, acc[t]))));
                }
            }
        }
        #pragma unroll
        for (int t = 0; t < TBLK; ++t) part[w][t][lane] = acc[t];
    }
    __syncthreads();                        // the ONLY barrier

    // ===== reduce quarters + softmax + argmax for this wave's 4 queries =====
    // score[t][j]: t = 4w+tt, j = lane.
    float4 strip;                           // p values, one per tt
    #pragma unroll
    for (int tt = 0; tt < 4; ++tt) {
        const int t = 4 * w + tt;
        float v = (part[0][t][lane] + part[1][t][lane] +
                   part[2][t][lane] + part[3][t][lane]) * 0.0625f;  // 1/sqrt(256)

        float m = v;
        #pragma unroll
        for (int off = 32; off; off >>= 1) m = fmaxf(m, __shfl_xor(m, off));

        float e = expf(v - m);
        float s = e;
        #pragma unroll
        for (int off = 32; off; off >>= 1) s += __shfl_xor(s, off);

        float pv = e / s;
        p_lds[t][lane] = pv;                // for PV (own wave reads back)
        ((float*)&strip)[tt] = pv;

        float av = v; int ai = lane;
        #pragma unroll
        for (int off = 32; off; off >>= 1) {
            float ov = __shfl_xor(av, off);
            int   oi = __shfl_xor(ai, off);
            if (ov > av || (ov == av && oi < ai)) { av = ov; ai = oi; }
        }
        if (lane == 0) maxatt[(size_t)b * TT + t0 + t] = (float)(prev + ai);
    }

    // ===== alignment strip straight from registers: row prev+lane, cols t0+4w.. =====
    // 16B per lane; 4 waves fill the 64B line; disjoint from zeroed rows.
    *(float4*)(aligns + ((size_t)b * NN + prev + lane) * TT + t0 + 4 * w) = strip;

    // ===== fused zeroing of this block's 15 non-window alignment rows =====
    {
        const int chunk = blockIdx.x & 63;
        float4* zbase = (float4*)(aligns + (size_t)b * NN * TT);
        const float4 z = make_float4(0.f, 0.f, 0.f, 0.f);
        #pragma unroll
        for (int r = 0; r < 15; ++r) {
            int idx = chunk * 15 + r;          // 0..959 among non-window rows
            int n   = idx < prev ? idx : idx + WIN;
            zbase[(size_t)n * 256 + tid] = z;  // 4KB contiguous per store-row
        }
    }

    // ================= PV direct from global (L2-hot V) ==================
    // lane = d-chunk (64 x float4 = 256 d); reads own wave's p rows (no barrier:
    // this wave wrote them; compiler inserts lgkmcnt).
    {
        const float* qb = Q + ((size_t)b * TT + t0 + 4 * w) * DD;
        const float4* V4 = (const float4*)(V + ((size_t)b * NN + prev) * DD);
        float4 o[4];
        #pragma unroll
        for (int t = 0; t < 4; ++t) o[t] = make_float4(0.f, 0.f, 0.f, 0.f);

        #pragma unroll 4
        for (int j4 = 0; j4 < WIN / 4; ++j4) {
            float4 p0 = *(const float4*)&p_lds[4 * w + 0][j4 * 4];  // uniform bcast
            float4 p1 = *(const float4*)&p_lds[4 * w + 1][j4 * 4];
            float4 p2 = *(const float4*)&p_lds[4 * w + 2][j4 * 4];
            float4 p3 = *(const float4*)&p_lds[4 * w + 3][j4 * 4];
            float4 v0 = V4[(size_t)(j4 * 4 + 0) * 64 + lane];
            float4 v1 = V4[(size_t)(j4 * 4 + 1) * 64 + lane];
            float4 v2 = V4[(size_t)(j4 * 4 + 2) * 64 + lane];
            float4 v3 = V4[(size_t)(j4 * 4 + 3) * 64 + lane];
            #define ACC4(o_, p_) \
                o_.x = fmaf(p_.x, v0.x, fmaf(p_.y, v1.x, fmaf(p_.z, v2.x, fmaf(p_.w, v3.x, o_.x)))); \
                o_.y = fmaf(p_.x, v0.y, fmaf(p_.y, v1.y, fmaf(p_.z, v2.y, fmaf(p_.w, v3.y, o_.y)))); \
                o_.z = fmaf(p_.x, v0.z, fmaf(p_.y, v1.z, fmaf(p_.z, v2.z, fmaf(p_.w, v3.z, o_.z)))); \
                o_.w = fmaf(p_.x, v0.w, fmaf(p_.y, v1.w, fmaf(p_.z, v2.w, fmaf(p_.w, v3.w, o_.w))));
            ACC4(o[0], p0) ACC4(o[1], p1) ACC4(o[2], p2) ACC4(o[3], p3)
            #undef ACC4
        }

        #pragma unroll
        for (int t = 0; t < 4; ++t) {
            float* Rrow = Rout + ((size_t)b * TT + t0 + 4 * w + t) * (2 * DD);
            ((float4*)Rrow)[lane] = o[t];                               // A@V
            ((float4*)(Rrow + DD))[lane] = ((const float4*)(qb + t * DD))[lane];  // Q copy
        }
    }
}

extern "C" void kernel_launch(void* const* d_in, const int* in_sizes, int n_in,
                              void* d_out, int out_size, void* d_ws, size_t ws_size,
                              hipStream_t stream) {
    const float* Q = (const float*)d_in[0];
    const float* K = (const float*)d_in[1];
    const float* V = (const float*)d_in[2];
    const int* prev = (const int*)d_in[3];
    float* out = (float*)d_out;

    // single fused launch: R, maxatt, window strip, AND non-window zeroing
    attn_v9<<<BB * TT / TBLK, NT, 0, stream>>>(Q, K, V, prev, out);
}

// Round 3
// 174.465 us; speedup vs baseline: 1.0024x; 1.0024x over previous
//
#include <hip/hip_runtime.h>

// B=16, T=1024, N=1024, D=256, WIN=64
// outputs (flat): R (B,T,2D) = [A@V, Q]   : 8388608 f32
//                 alignments (B,N,T) = A^T: 16777216 f32
//                 max_att (B,T)           : 16384 f32
//
// v10: one barrier, coalesced staging. v8 = 59.5us with 4 barrier drains;
// v9 showed uncoalesced K reads cost more than barriers save. So: keep v8's
// staged-K QK^T (coalesced, LDS, lane=key-row) but stage the FULL K window
// once per block:
//  - 512 threads (8 waves), TBLK=32 queries, grid 512 = 2 blocks/CU,
//    16 waves/CU (same occupancy as v8, half the phase-locked blocks).
//  - ks[64][260]: 66.5KB, one coalesced stage, ONE __syncthreads total.
//    260%32==4 -> same 2-way (free) bank pattern as v8's LSTR=132.
//  - softmax wave-local; alignment strip stored from registers (no transpose
//    barrier); p_lds rows written+read by the same wave (no barrier pre-PV).
//  - non-window zeroing fused, issued after QK^T before PV (v8 placement).
//  - d-accumulation sequential 0..255 (v8 order) -> absmax back to ~0.002.

#define BB 16
#define TT 1024
#define NN 1024
#define DD 256
#define WIN 64
#define TBLK 32          // queries per block
#define NT 512           // 8 waves, 4 queries each

#define R_ELEMS   (16u*1024u*512u)        // 8388608
#define ALN_ELEMS (16u*1024u*1024u)       // 16777216

#define LSTR 260         // LDS row stride (floats); 260%32==4 -> 2-way (free) b128

__global__ __launch_bounds__(NT, 4) void attn_v10(
    const float* __restrict__ Q, const float* __restrict__ K,
    const float* __restrict__ V, const int* __restrict__ prev_in,
    float* __restrict__ out)
{
    __shared__ float ks[WIN * LSTR];        // 66560 B: full K window
    __shared__ float p_lds[TBLK][WIN + 4];  //  8704 B: probabilities [t][j]

    float* Rout   = out;
    float* aligns = out + R_ELEMS;
    float* maxatt = out + R_ELEMS + ALN_ELEMS;

    const int tid  = threadIdx.x;
    const int lane = tid & 63;
    const int w    = __builtin_amdgcn_readfirstlane(tid >> 6);  // wave 0..7 (uniform)
    const int b    = blockIdx.x >> 5;       // 32 blocks per batch
    const int t0   = (blockIdx.x & 31) * TBLK;
    const int prev = prev_in[b];

    const float* qb = Q + ((size_t)b * TT + t0 + 4 * w) * DD;   // wave-uniform base

    // ============== stage full K window (coalesced), ONE barrier ==============
    {
        const float4* Ksrc = (const float4*)(K + ((size_t)b * NN + prev) * DD);
        #pragma unroll
        for (int k = 0; k < 8; ++k) {
            int t4 = tid + k * NT;          // 0..4095 float4 chunks
            int r = t4 >> 6, c = t4 & 63;   // row 0..63, col-chunk 0..63
            float4 v = Ksrc[(size_t)r * 64 + c];
            *(float4*)&ks[r * LSTR + c * 4] = v;
        }
    }
    __syncthreads();                        // the ONLY barrier

    // ================= QK^T: lane = key row j, full 256 dims =================
    float acc[4] = {0.f, 0.f, 0.f, 0.f};
    #pragma unroll 8
    for (int d4 = 0; d4 < 64; ++d4) {
        float4 kk = *(const float4*)&ks[lane * LSTR + d4 * 4];  // 2-way, free
        #pragma unroll
        for (int t = 0; t < 4; ++t) {
            float4 q = ((const float4*)(qb + t * DD))[d4];      // wave-uniform (s_load)
            acc[t] = fmaf(q.x, kk.x, fmaf(q.y, kk.y, fmaf(q.z, kk.z, fmaf(q.w, kk.w, acc[t]))));
        }
    }

    // ===== softmax + argmax (wave-local), p -> LDS + strip registers =====
    float4 strip;
    #pragma unroll
    for (int tt = 0; tt < 4; ++tt) {
        const int t = 4 * w + tt;
        float v = acc[tt] * 0.0625f;        // 1/sqrt(256)

        float m = v;
        #pragma unroll
        for (int off = 32; off; off >>= 1) m = fmaxf(m, __shfl_xor(m, off));

        float e = expf(v - m);
        float s = e;
        #pragma unroll
        for (int off = 32; off; off >>= 1) s += __shfl_xor(s, off);

        float pv = e / s;
        p_lds[t][lane] = pv;                // own wave reads back in PV
        ((float*)&strip)[tt] = pv;

        float av = v; int ai = lane;
        #pragma unroll
        for (int off = 32; off; off >>= 1) {
            float ov = __shfl_xor(av, off);
            int   oi = __shfl_xor(ai, off);
            if (ov > av || (ov == av && oi < ai)) { av = ov; ai = oi; }
        }
        if (lane == 0) maxatt[(size_t)b * TT + t0 + t] = (float)(prev + ai);
    }

    // ===== alignment strip from registers: row prev+lane, cols t0+4w.. =====
    *(float4*)(aligns + ((size_t)b * NN + prev + lane) * TT + t0 + 4 * w) = strip;

    // ===== fused zeroing of this block's 30 non-window alignment rows =====
    // 512 threads cover 2 rows (2 x 4KB) per iteration.
    {
        const int chunk = blockIdx.x & 31;
        float4* zbase = (float4*)(aligns + (size_t)b * NN * TT);
        const float4 z = make_float4(0.f, 0.f, 0.f, 0.f);
        #pragma unroll
        for (int r = 0; r < 15; ++r) {
            int idx = chunk * 30 + 2 * r + (tid >> 8);   // 0..959 among non-window rows
            int n   = idx < prev ? idx : idx + WIN;
            zbase[(size_t)n * 256 + (tid & 255)] = z;
        }
    }

    // ================= PV direct from global (L2-hot V) ==================
    // lane = d-chunk (64 x float4 = 256 d); reads own wave's p rows (lgkmcnt
    // dependency only, no barrier).
    {
        const float4* V4 = (const float4*)(V + ((size_t)b * NN + prev) * DD);
        float4 o[4];
        #pragma unroll
        for (int t = 0; t < 4; ++t) o[t] = make_float4(0.f, 0.f, 0.f, 0.f);

        #pragma unroll 4
        for (int j4 = 0; j4 < WIN / 4; ++j4) {
            float4 p0 = *(const float4*)&p_lds[4 * w + 0][j4 * 4];  // uniform bcast
            float4 p1 = *(const float4*)&p_lds[4 * w + 1][j4 * 4];
            float4 p2 = *(const float4*)&p_lds[4 * w + 2][j4 * 4];
            float4 p3 = *(const float4*)&p_lds[4 * w + 3][j4 * 4];
            float4 v0 = V4[(size_t)(j4 * 4 + 0) * 64 + lane];
            float4 v1 = V4[(size_t)(j4 * 4 + 1) * 64 + lane];
            float4 v2 = V4[(size_t)(j4 * 4 + 2) * 64 + lane];
            float4 v3 = V4[(size_t)(j4 * 4 + 3) * 64 + lane];
            #define ACC4(o_, p_) \
                o_.x = fmaf(p_.x, v0.x, fmaf(p_.y, v1.x, fmaf(p_.z, v2.x, fmaf(p_.w, v3.x, o_.x)))); \
                o_.y = fmaf(p_.x, v0.y, fmaf(p_.y, v1.y, fmaf(p_.z, v2.y, fmaf(p_.w, v3.y, o_.y)))); \
                o_.z = fmaf(p_.x, v0.z, fmaf(p_.y, v1.z, fmaf(p_.z, v2.z, fmaf(p_.w, v3.z, o_.z)))); \
                o_.w = fmaf(p_.x, v0.w, fmaf(p_.y, v1.w, fmaf(p_.z, v2.w, fmaf(p_.w, v3.w, o_.w))));
            ACC4(o[0], p0) ACC4(o[1], p1) ACC4(o[2], p2) ACC4(o[3], p3)
            #undef ACC4
        }

        #pragma unroll
        for (int t = 0; t < 4; ++t) {
            float* Rrow = Rout + ((size_t)b * TT + t0 + 4 * w + t) * (2 * DD);
            ((float4*)Rrow)[lane] = o[t];                               // A@V
            ((float4*)(Rrow + DD))[lane] = ((const float4*)(qb + t * DD))[lane];  // Q copy
        }
    }
}

extern "C" void kernel_launch(void* const* d_in, const int* in_sizes, int n_in,
                              void* d_out, int out_size, void* d_ws, size_t ws_size,
                              hipStream_t stream) {
    const float* Q = (const float*)d_in[0];
    const float* K = (const float*)d_in[1];
    const float* V = (const float*)d_in[2];
    const int* prev = (const int*)d_in[3];
    float* out = (float*)d_out;

    // single fused launch: R, maxatt, window strip, AND non-window zeroing
    attn_v10<<<BB * TT / TBLK, NT, 0, stream>>>(Q, K, V, prev, out);
}

// Round 4
// 160.302 us; speedup vs baseline: 1.0910x; 1.0884x over previous
//
#include <hip/hip_runtime.h>

// B=16, T=1024, N=1024, D=256, WIN=64
// outputs (flat): R (B,T,2D) = [A@V, Q]   : 8388608 f32
//                 alignments (B,N,T) = A^T: 16777216 f32
//                 max_att (B,T)           : 16384 f32
//
// v11: heterogeneous grid — decouple streaming zero-stores from compute at
// the BLOCK level (one launch), instead of fusing them into the compute
// wave's instruction stream (v8) or a serial second kernel (v7).
//   Why: vmcnt retires in-order. v8's fused zero-stores sat ahead of PV's
//   V-loads in every wave's VMEM queue, so PV's first s_waitcnt forced the
//   machine-wide ~60MB zero drain onto the critical path (all blocks
//   phase-locked). v9/v10 showed barriers are NOT the bottleneck.
//  - blocks 0..239: pure zero-streaming, 64 non-window rows each (256KB).
//    First in dispatch order -> occupy slots ~3us, vacate, drain overlaps
//    the remaining ~35us of attention compute (which only uses ~2TB/s).
//  - blocks 240..1263: v8 attention structure verbatim, minus zero loop,
//    plus Q->R copy hoisted to the top (second Q read becomes L2-hit;
//    v8's FETCH=33MB showed Q was fetched twice from HBM).

#define BB 16
#define TT 1024
#define NN 1024
#define DD 256
#define WIN 64
#define TBLK 16          // queries per attn block
#define NT 256           // 4 waves, 4 queries each
#define NZ 240           // zero-streaming blocks (16 batches x 15)

#define R_ELEMS   (16u*1024u*512u)        // 8388608
#define ALN_ELEMS (16u*1024u*1024u)       // 16777216

#define LSTR 132         // LDS row stride (dwords); 132%32==4 -> conflict-free b128

__global__ __launch_bounds__(NT, 4) void attn_v11(
    const float* __restrict__ Q, const float* __restrict__ K,
    const float* __restrict__ V, const int* __restrict__ prev_in,
    float* __restrict__ out)
{
    __shared__ float ks[WIN * LSTR];        // 33792 B: K half-tile
    __shared__ float p_lds[TBLK][WIN + 4];  // 4352 B : probabilities [t][j]

    float* Rout   = out;
    float* aligns = out + R_ELEMS;
    float* maxatt = out + R_ELEMS + ALN_ELEMS;

    const int tid = threadIdx.x;

    // ================= role 1: zero-streaming blocks =================
    if (blockIdx.x < NZ) {
        const int zb    = blockIdx.x;
        const int b     = zb / 15;          // 15 blocks per batch
        const int chunk = zb % 15;          // 64 rows each
        const int prev  = prev_in[b];
        float4* zbase = (float4*)(aligns + (size_t)b * NN * TT);
        const float4 z = make_float4(0.f, 0.f, 0.f, 0.f);
        #pragma unroll 8
        for (int r = 0; r < 64; ++r) {
            int idx = chunk * 64 + r;          // 0..959 among non-window rows
            int n   = idx < prev ? idx : idx + WIN;
            zbase[(size_t)n * 256 + tid] = z;  // 4KB contiguous per row
        }
        return;                                // wave dies; stores drain async
    }

    // ================= role 2: attention blocks (v8 core) =================
    const int aid  = blockIdx.x - NZ;
    const int lane = tid & 63;
    const int w    = __builtin_amdgcn_readfirstlane(tid >> 6);  // wave 0..3
    const int b    = aid >> 6;              // 64 blocks per batch
    const int t0   = (aid & 63) * TBLK;
    const int prev = prev_in[b];

    const float* qb = Q + ((size_t)b * TT + t0 + 4 * w) * DD;   // wave-uniform base

    // ---- hoisted Q copy: warms L2 for the QK s_load stream, shortens tail ----
    #pragma unroll
    for (int t = 0; t < 4; ++t) {
        float4 qv = ((const float4*)(qb + t * DD))[lane];
        float* Rrow = Rout + ((size_t)b * TT + t0 + 4 * w + t) * (2 * DD);
        ((float4*)(Rrow + DD))[lane] = qv;
    }

    // ================= QK^T over two 128-d halves =================
    float acc[4] = {0.f, 0.f, 0.f, 0.f};
    #pragma unroll
    for (int h = 0; h < 2; ++h) {
        if (h) __syncthreads();             // h0 readers done before restage
        const float4* Ksrc = (const float4*)(K + ((size_t)b * NN + prev) * DD + h * 128);
        #pragma unroll
        for (int k = 0; k < 8; ++k) {
            int t4 = tid + k * NT;          // 0..2047 float4 chunks
            int r = t4 >> 5, c = t4 & 31;
            float4 v = Ksrc[(size_t)r * 64 + c];
            *(float4*)&ks[r * LSTR + c * 4] = v;
        }
        __syncthreads();

        const float* qh = qb + h * 128;
        #pragma unroll 8
        for (int d4 = 0; d4 < 32; ++d4) {
            float4 kk = *(const float4*)&ks[lane * LSTR + d4 * 4];  // conflict-free b128
            #pragma unroll
            for (int t = 0; t < 4; ++t) {
                float4 q = ((const float4*)(qh + t * DD))[d4];      // wave-uniform
                acc[t] = fmaf(q.x, kk.x, fmaf(q.y, kk.y, fmaf(q.z, kk.z, fmaf(q.w, kk.w, acc[t]))));
            }
        }
    }

    // ================= softmax + argmax (wave-local), p -> LDS ===========
    #pragma unroll
    for (int t = 0; t < 4; ++t) {
        float v = acc[t] * 0.0625f;         // 1/sqrt(256)

        float m = v;
        #pragma unroll
        for (int off = 32; off; off >>= 1) m = fmaxf(m, __shfl_xor(m, off));

        float e = expf(v - m);
        float s = e;
        #pragma unroll
        for (int off = 32; off; off >>= 1) s += __shfl_xor(s, off);

        p_lds[4 * w + t][lane] = e / s;

        float av = v; int ai = lane;
        #pragma unroll
        for (int off = 32; off; off >>= 1) {
            float ov = __shfl_xor(av, off);
            int   oi = __shfl_xor(ai, off);
            if (ov > av || (ov == av && oi < ai)) { av = ov; ai = oi; }
        }
        if (lane == 0) maxatt[(size_t)b * TT + t0 + 4 * w + t] = (float)(prev + ai);
    }
    __syncthreads();                        // all 16 p rows visible

    // ===== window-row alignment strip: 64 rows x 16 floats (64B lines) ====
    // Zero blocks never touch these rows -> written exactly once.
    {
        const int j = tid >> 2, cg = tid & 3;
        float4 v;
        v.x = p_lds[cg * 4 + 0][j];
        v.y = p_lds[cg * 4 + 1][j];
        v.z = p_lds[cg * 4 + 2][j];
        v.w = p_lds[cg * 4 + 3][j];
        *(float4*)(aligns + ((size_t)b * NN + prev + j) * TT + t0 + cg * 4) = v;
    }

    // ================= PV direct from global (L2-hot V) ==================
    // lane = d-chunk (64 x float4 = 256 d); reads own wave's p rows.
    {
        const float4* V4 = (const float4*)(V + ((size_t)b * NN + prev) * DD);
        float4 o[4];
        #pragma unroll
        for (int t = 0; t < 4; ++t) o[t] = make_float4(0.f, 0.f, 0.f, 0.f);

        #pragma unroll 4
        for (int j4 = 0; j4 < WIN / 4; ++j4) {
            float4 p0 = *(const float4*)&p_lds[4 * w + 0][j4 * 4];  // uniform bcast
            float4 p1 = *(const float4*)&p_lds[4 * w + 1][j4 * 4];
            float4 p2 = *(const float4*)&p_lds[4 * w + 2][j4 * 4];
            float4 p3 = *(const float4*)&p_lds[4 * w + 3][j4 * 4];
            float4 v0 = V4[(size_t)(j4 * 4 + 0) * 64 + lane];
            float4 v1 = V4[(size_t)(j4 * 4 + 1) * 64 + lane];
            float4 v2 = V4[(size_t)(j4 * 4 + 2) * 64 + lane];
            float4 v3 = V4[(size_t)(j4 * 4 + 3) * 64 + lane];
            #define ACC4(o_, p_) \
                o_.x = fmaf(p_.x, v0.x, fmaf(p_.y, v1.x, fmaf(p_.z, v2.x, fmaf(p_.w, v3.x, o_.x)))); \
                o_.y = fmaf(p_.x, v0.y, fmaf(p_.y, v1.y, fmaf(p_.z, v2.y, fmaf(p_.w, v3.y, o_.y)))); \
                o_.z = fmaf(p_.x, v0.z, fmaf(p_.y, v1.z, fmaf(p_.z, v2.z, fmaf(p_.w, v3.z, o_.z)))); \
                o_.w = fmaf(p_.x, v0.w, fmaf(p_.y, v1.w, fmaf(p_.z, v2.w, fmaf(p_.w, v3.w, o_.w))));
            ACC4(o[0], p0) ACC4(o[1], p1) ACC4(o[2], p2) ACC4(o[3], p3)
            #undef ACC4
        }

        #pragma unroll
        for (int t = 0; t < 4; ++t) {
            float* Rrow = Rout + ((size_t)b * TT + t0 + 4 * w + t) * (2 * DD);
            ((float4*)Rrow)[lane] = o[t];   // A@V (Q half already written)
        }
    }
}

extern "C" void kernel_launch(void* const* d_in, const int* in_sizes, int n_in,
                              void* d_out, int out_size, void* d_ws, size_t ws_size,
                              hipStream_t stream) {
    const float* Q = (const float*)d_in[0];
    const float* K = (const float*)d_in[1];
    const float* V = (const float*)d_in[2];
    const int* prev = (const int*)d_in[3];
    float* out = (float*)d_out;

    // single launch: 240 zero-streaming blocks first, then 1024 attn blocks
    attn_v11<<<NZ + BB * TT / TBLK, NT, 0, stream>>>(Q, K, V, prev, out);
}